// Round 4
// baseline (117.113 us; speedup 1.0000x reference)
//
#include <hip/hip_runtime.h>

typedef _Float16 half4_t __attribute__((ext_vector_type(4)));
typedef float floatx4 __attribute__((ext_vector_type(4)));

static constexpr int HW = 128;  // H == W == 128
static constexpr int DD = 64;   // D

// Block = (b, rc, eighth e8): 16 output rows. NO LDS, NO barrier.
// All 4 waves redundantly compute the same 16-row softmax fully in registers,
// directly in mfma A-fragment layout; each wave owns a distinct 16-col slice
// of V/out. Each wave is one straight-line load->compute pipeline.
//   lane layout: row = lane&15 (P row), kgrp = (lane>>4)*4, col = 16*wave + (lane&15)
//   lane owns j = 16t + kgrp + i  (t=0..7, i=0..3)  -> full row = 4 lanes
//   row-reduce = shfl_xor 16, 32.
// X: brc=(b,r), P rows are c, softmax over j, V=v[b,r,:,:] (k-stride 64).
// Y: brc=(b,c), P rows are r, softmax over i, V=v[b,:,c,:] (k-stride 8192); out +=.
template<bool IS_Y>
__global__ __launch_bounds__(256)
void axial_attn(const float* __restrict__ atten,
                const float* __restrict__ vsrc,
                const float* __restrict__ shift_p,
                float* __restrict__ out)
{
    const int blk   = blockIdx.x;
    const int e8    = blk & 7;          // eighth; consecutive blocks share brc
    const int brc   = blk >> 3;
    const int b     = brc >> 7;
    const int rc    = brc & 127;
    const int rbase = e8 * 16;
    const int tid   = threadIdx.x;
    const int w     = tid >> 6;
    const int lane  = tid & 63;
    const int lr    = lane & 15;
    const int kgrp  = (lane >> 4) * 4;
    const int col   = 16 * w + lr;
    const int row   = rbase + lr;       // this lane's P row (c for X, r for Y)

    // ---- issue atten loads first (softmax is the long dependent chain) ----
    const float* arow = atten + (size_t)brc * (HW * HW) + (size_t)row * HW + kgrp;
    floatx4 a[8];
    #pragma unroll
    for (int t = 0; t < 8; ++t) a[t] = *(const floatx4*)(arow + t * 16);

    // ---- issue V loads (B-fragment elements, 64B-coalesced per 16-lane group) ----
    const float* vb  = IS_Y ? vsrc + (size_t)b * (HW * HW * DD) + (size_t)rc * DD
                            : vsrc + (size_t)brc * (HW * DD);
    const int    vst = IS_Y ? HW * DD : DD;
    float vr[32];
    #pragma unroll
    for (int t = 0; t < 8; ++t)
        #pragma unroll
        for (int i = 0; i < 4; ++i)
            vr[t * 4 + i] = vb[(size_t)(t * 16 + kgrp + i) * vst + col];

    // ---- Y: preload out straight into the accumulator ----
    float* obase  = IS_Y ? out + (size_t)b * (HW * HW * DD) + (size_t)rc * DD
                         : out + (size_t)brc * (HW * DD);
    const int ost = IS_Y ? HW * DD : DD;
    floatx4 acc;
    if (IS_Y) {
        #pragma unroll
        for (int i = 0; i < 4; ++i)
            acc[i] = obase[(size_t)(rbase + kgrp + i) * ost + col];
    } else {
        acc = (floatx4)(0.f);
    }

    const float shift = shift_p[0];     // bias cancels in softmax

    // ---- in-register softmax of row `row` ----
    float l[32];
    #pragma unroll
    for (int t = 0; t < 8; ++t)
        #pragma unroll
        for (int i = 0; i < 4; ++i) {
            const float d = (float)(16 * t + kgrp + i - row);
            l[t * 4 + i] = fmaf(-shift * d, d, a[t][i]);
        }
    float m16[16];
    #pragma unroll
    for (int i = 0; i < 16; ++i) m16[i] = fmaxf(l[i], l[i + 16]);
    #pragma unroll
    for (int s = 8; s >= 1; s >>= 1)
        #pragma unroll
        for (int i = 0; i < s; ++i) m16[i] = fmaxf(m16[i], m16[i + s]);
    float mx = m16[0];
    mx = fmaxf(mx, __shfl_xor(mx, 16));
    mx = fmaxf(mx, __shfl_xor(mx, 32));

    float e[32];
    #pragma unroll
    for (int t = 0; t < 32; ++t) e[t] = __expf(l[t] - mx);
    float s16[16];
    #pragma unroll
    for (int i = 0; i < 16; ++i) s16[i] = e[i] + e[i + 16];
    #pragma unroll
    for (int s = 8; s >= 1; s >>= 1)
        #pragma unroll
        for (int i = 0; i < s; ++i) s16[i] += s16[i + s];
    float sum = s16[0];
    sum += __shfl_xor(sum, 16);
    sum += __shfl_xor(sum, 32);
    const float inv = 1.0f / sum;

    // ---- fragments: A from softmax, B from prefetched V ----
    half4_t af[8], bf[8];
    #pragma unroll
    for (int t = 0; t < 8; ++t)
        #pragma unroll
        for (int i = 0; i < 4; ++i) {
            af[t][i] = (_Float16)(e[t * 4 + i] * inv);
            bf[t][i] = (_Float16)vr[t * 4 + i];
        }

    // ---- MFMA: A[row=lane&15][k=kgrp+i], B[k][col], D[col][row=kgrp+i] ----
    #pragma unroll
    for (int t = 0; t < 8; ++t)
        acc = __builtin_amdgcn_mfma_f32_16x16x16f16(af[t], bf[t], acc, 0, 0, 0);

    // ---- store ----
    #pragma unroll
    for (int i = 0; i < 4; ++i)
        obase[(size_t)(rbase + kgrp + i) * ost + col] = acc[i];
}

extern "C" void kernel_launch(void* const* d_in, const int* in_sizes, int n_in,
                              void* d_out, int out_size, void* d_ws, size_t ws_size,
                              hipStream_t stream)
{
    // inputs: 0=x (unused), 1=atten_x_full, 2=atten_y_full, 3=value_full, 4=shift, 5=bias (cancels)
    const float* atx   = (const float*)d_in[1];
    const float* aty   = (const float*)d_in[2];
    const float* val   = (const float*)d_in[3];
    const float* shift = (const float*)d_in[4];
    float* out = (float*)d_out;

    axial_attn<false><<<dim3(8 * 128 * 8), dim3(256), 0, stream>>>(atx, val, shift, out);
    axial_attn<true ><<<dim3(8 * 128 * 8), dim3(256), 0, stream>>>(aty, val, shift, out);
}

// Round 5
// 63.492 us; speedup vs baseline: 1.8445x; 1.8445x over previous
//
#include <hip/hip_runtime.h>
#include <stdint.h>

typedef _Float16 half4_t __attribute__((ext_vector_type(4)));
typedef _Float16 half8_t __attribute__((ext_vector_type(8)));
typedef float floatx4 __attribute__((ext_vector_type(4)));

static constexpr int HW  = 128;
static constexpr int DD  = 64;
static constexpr int RPB = 64;    // output rows per block (half of 128)

typedef const __attribute__((address_space(1))) uint32_t GU;
typedef __attribute__((address_space(3))) uint32_t LU;

// Block = (b, rc, half h): 64 output rows of OUT = softmax(logits) @ V.
// All staging via async global_load_lds (width 16) issued at block entry:
//   AT [64][128] f32 (32KB)  -- atten rows; overwritten in-place by P (f16, swizzled)
//   VL [128][64] f32 (32KB)  -- V rows
// Wave w stages AND softmaxes rows [16w..16w+16) -> per-wave vmcnt(8) suffices
// before softmax (no barrier); one __syncthreads() before MFMA drains VL.
// X: brc=(b,r), P rows are c, V=v[b,r,:,:] contiguous.   out = P@V
// Y: brc=(b,c), P rows are r, V=v[b,:,c,:] (k-stride 8192); out += (preload acc).
template<bool IS_Y>
__global__ __launch_bounds__(256, 2)
void axial_attn(const float* __restrict__ atten,
                const float* __restrict__ vsrc,
                const float* __restrict__ shift_p,
                float* __restrict__ out)
{
    __shared__ float ATf[RPB * HW];   // 32 KB, becomes P (f16) in place
    __shared__ float VL [HW * DD];    // 32 KB

    const int blk   = blockIdx.x;
    const int h     = blk & 1;        // halves adjacent -> V L2 reuse
    const int brc   = blk >> 1;
    const int b     = brc >> 7;
    const int rc    = brc & 127;
    const int rbase = h * RPB;
    const int tid   = threadIdx.x;
    const int w     = tid >> 6;
    const int lane  = tid & 63;
    const int lr    = lane & 15;
    const int g     = lane >> 4;      // 0..3

    char* ATb = (char*)ATf;

    // ---- issue async staging: AT first (8 segs/wave), then VL (8 segs/wave) ----
    {
        const char* ag = (const char*)(atten + (size_t)brc * (HW * HW) + (size_t)rbase * HW);
        #pragma unroll
        for (int i = 0; i < 8; ++i) {
            const int seg = w * 8 + i;              // wave w stages its own softmax rows
            __builtin_amdgcn_global_load_lds((GU*)(ag + seg * 1024 + lane * 16),
                                             (LU*)(ATb + seg * 1024), 16, 0, 0);
        }
        char* VLb = (char*)VL;
        if (!IS_Y) {
            const char* vg = (const char*)(vsrc + (size_t)brc * (HW * DD));
            #pragma unroll
            for (int i = 0; i < 8; ++i) {
                const int seg = w * 8 + i;
                __builtin_amdgcn_global_load_lds((GU*)(vg + seg * 1024 + lane * 16),
                                                 (LU*)(VLb + seg * 1024), 16, 0, 0);
            }
        } else {
            const char* vg = (const char*)(vsrc + ((size_t)b * (HW * HW) + rc) * DD);
            #pragma unroll
            for (int i = 0; i < 8; ++i) {
                const int seg = w * 8 + i;
                const int o   = seg * 1024 + lane * 16;   // linear LDS byte offset
                const int k   = o >> 8;                    // 256 B per k-row
                const int within = o & 255;
                __builtin_amdgcn_global_load_lds((GU*)(vg + (size_t)k * (HW * DD * 4) + within),
                                                 (LU*)(VLb + o), 16, 0, 0);
            }
        }
    }

    // wait for this wave's 8 AT segs (8 VL segs stay in flight)
    asm volatile("s_waitcnt vmcnt(8)" ::: "memory");

    // ---- Y: issue out-preload now; latency hides under softmax ----
    float* obase;
    size_t ostr;
    if (IS_Y) { obase = out + ((size_t)b * HW + rbase) * (HW * DD) + (size_t)rc * DD; ostr = HW * DD; }
    else      { obase = out + (size_t)brc * (HW * DD) + (size_t)rbase * DD;           ostr = DD; }
    floatx4 acc[4];
    if (IS_Y) {
        #pragma unroll
        for (int tr = 0; tr < 4; ++tr)
            #pragma unroll
            for (int i = 0; i < 4; ++i)
                acc[tr][i] = obase[(size_t)(16 * tr + 4 * g + i) * ostr + 16 * w + lr];
    } else {
        #pragma unroll
        for (int tr = 0; tr < 4; ++tr) acc[tr] = (floatx4)(0.f);
    }

    const float shift = shift_p[0];   // bias cancels in softmax

    // ---- softmax: wave w owns rows [16w..16w+16), 4 rows/iter (16 lanes x 8 elems) ----
    #pragma unroll
    for (int it = 0; it < 4; ++it) {
        const int row_l = 16 * w + 4 * it + g;
        const int row_g = rbase + row_l;
        const floatx4 a0 = *(const floatx4*)&ATf[row_l * HW + lr * 8];
        const floatx4 a1 = *(const floatx4*)&ATf[row_l * HW + lr * 8 + 4];
        float l[8];
        #pragma unroll
        for (int u = 0; u < 8; ++u) {
            const float a = (u < 4) ? a0[u] : a1[u - 4];
            const float d = (float)(lr * 8 + u - row_g);
            l[u] = fmaf(-shift * d, d, a);
        }
        float m = fmaxf(fmaxf(fmaxf(l[0], l[1]), fmaxf(l[2], l[3])),
                        fmaxf(fmaxf(l[4], l[5]), fmaxf(l[6], l[7])));
        #pragma unroll
        for (int s = 8; s; s >>= 1) m = fmaxf(m, __shfl_xor(m, s));
        float e[8], ssum = 0.f;
        #pragma unroll
        for (int u = 0; u < 8; ++u) { e[u] = __expf(l[u] - m); ssum += e[u]; }
        #pragma unroll
        for (int s = 8; s; s >>= 1) ssum += __shfl_xor(ssum, s);
        const float inv = 1.0f / ssum;
        half8_t ph;
        #pragma unroll
        for (int u = 0; u < 8; ++u) ph[u] = (_Float16)(e[u] * inv);
        // in-place P write: row row_l, kbytes [16*lr..+16) XOR-swizzled by row
        *(half8_t*)(ATb + row_l * 512 + ((lr * 16) ^ ((row_l & 7) << 4))) = ph;
    }

    __syncthreads();   // drains vmcnt(0): VL + preloads; lgkm: P writes

    // ---- MFMA: wave w -> cols [16w..16w+16), rows 0..63 (4 tiles) ----
    // A[row=lane&15][k=4g+i], B[k][col=lane&15], D[col][row=4g+i]
    #pragma unroll
    for (int t = 0; t < 8; ++t) {
        half4_t bf;
        #pragma unroll
        for (int i = 0; i < 4; ++i)
            bf[i] = (_Float16)VL[(16 * t + 4 * g + i) * DD + 16 * w + lr];
        #pragma unroll
        for (int tr = 0; tr < 4; ++tr) {
            const int prow = 16 * tr + lr;
            const half4_t af = *(const half4_t*)(ATb + prow * 512
                                                 + ((32 * t + 8 * g) ^ ((prow & 7) << 4)));
            acc[tr] = __builtin_amdgcn_mfma_f32_16x16x16f16(af, bf, acc[tr], 0, 0, 0);
        }
    }

    // ---- store: D[col=16w+lr][row=16tr+4g+i] ----
    #pragma unroll
    for (int tr = 0; tr < 4; ++tr)
        #pragma unroll
        for (int i = 0; i < 4; ++i)
            obase[(size_t)(16 * tr + 4 * g + i) * ostr + 16 * w + lr] = acc[tr][i];
}

extern "C" void kernel_launch(void* const* d_in, const int* in_sizes, int n_in,
                              void* d_out, int out_size, void* d_ws, size_t ws_size,
                              hipStream_t stream)
{
    // inputs: 0=x (unused), 1=atten_x_full, 2=atten_y_full, 3=value_full, 4=shift, 5=bias (cancels)
    const float* atx   = (const float*)d_in[1];
    const float* aty   = (const float*)d_in[2];
    const float* val   = (const float*)d_in[3];
    const float* shift = (const float*)d_in[4];
    float* out = (float*)d_out;

    axial_attn<false><<<dim3(8 * 128 * 2), dim3(256), 0, stream>>>(atx, val, shift, out);
    axial_attn<true ><<<dim3(8 * 128 * 2), dim3(256), 0, stream>>>(aty, val, shift, out);
}